// Round 4
// baseline (23603.752 us; speedup 1.0000x reference)
//
#include <hip/hip_runtime.h>

// 16-qubit statevector sim, 512 samples, one sample per 512-thread block.
// amp index i (16 bits): bits 0..6 = thread-local (128 amps/thread),
// bits 7..12 = lane (tid&63), bits 13..15 = wave (tid>>6). Qubit q <-> bit 15-q.
// State: amps l<96 in registers (sr/si), l in [96,128) in LDS sL[l-96][tid].
// Gates with lane/wave-bit targets use ONE runtime-parameterized body each
// (shuffle masks / partner tids / control-bit tests are runtime values);
// only local-bit targets are templated (register arrays need constexpr idx).
// This keeps total code ~13k instrs (round-1's 45k blew compile limits).

#define NREG 96
#define NLDS 32
#define NTH  512
#define SMEM_BYTES (NLDS * NTH * 8 + 2 * NTH * 16)  // 131072 + 16384 = 147456

template <int I> struct IC { static constexpr int value = I; };

template <int N, int I = 0, typename F>
__device__ __forceinline__ void static_for(F&& f) {
  if constexpr (I < N) {
    f(IC<I>{});
    static_for<N, I + 1>(f);
  }
}

template <int P> __device__ constexpr int ins0(int h) {
  return ((h >> P) << (P + 1)) | (h & ((1 << P) - 1));
}

#define SARGS float (&sr)[NREG], float (&si)[NREG], float2 (*sL)[NTH], float4 (*stg)[NTH], const int tid
#define SPASS sr, si, sL, stg, tid

template <int L>
__device__ __forceinline__ float2 ldS(SARGS) {
  static_assert(L >= 0 && L < 128, "amp idx");
  if constexpr (L < NREG) return make_float2(sr[L], si[L]);
  else return sL[L - NREG][tid];
}

template <int L>
__device__ __forceinline__ void stS(SARGS, float2 v) {
  static_assert(L >= 0 && L < 128, "amp idx");
  if constexpr (L < NREG) { sr[L] = v.x; si[L] = v.y; }
  else sL[L - NREG][tid] = v;
}

// ---------- Rot on local bit J (templated target, runtime u) ----------
template <int J>
__device__ __forceinline__ void rot_local(SARGS, const float* __restrict__ u) {
  const float u00r = u[0], u00i = u[1], u01r = u[2], u01i = u[3];
  const float u10r = u[4], u10i = u[5], u11r = u[6], u11i = u[7];
  static_for<64>([&](auto hc) {
    constexpr int h = hc.value;
    constexpr int i0 = ins0<J>(h);
    constexpr int i1 = i0 | (1 << J);
    const float2 a = ldS<i0>(SPASS);
    const float2 b = ldS<i1>(SPASS);
    float2 n0, n1;
    n0.x = u00r * a.x - u00i * a.y + u01r * b.x - u01i * b.y;
    n0.y = u00r * a.y + u00i * a.x + u01r * b.y + u01i * b.x;
    n1.x = u10r * a.x - u10i * a.y + u11r * b.x - u11i * b.y;
    n1.y = u10r * a.y + u10i * a.x + u11r * b.y + u11i * b.x;
    stS<i0>(SPASS, n0);
    stS<i1>(SPASS, n1);
  });
}

// ---------- Rot on lane bit (runtime lane-bit index jm in [0,6)) ----------
__device__ __forceinline__ void rot_lane(SARGS, const float* __restrict__ u, const int jm) {
  const int m = 1 << jm;
  const int bit = (tid >> jm) & 1;
  const float car = bit ? u[6] : u[0], cai = bit ? u[7] : u[1];
  const float cbr = bit ? u[4] : u[2], cbi = bit ? u[5] : u[3];
  static_for<NREG>([&](auto ic) {
    constexpr int i = ic.value;
    const float orr = sr[i], oii = si[i];
    const float pr = __shfl_xor(orr, m);
    const float pi = __shfl_xor(oii, m);
    sr[i] = car * orr - cai * oii + cbr * pr - cbi * pi;
    si[i] = car * oii + cai * orr + cbr * pi + cbi * pr;
  });
  static_for<NLDS>([&](auto kc) {
    constexpr int k = kc.value;
    const float2 o = sL[k][tid];
    const float px = __shfl_xor(o.x, m);
    const float py = __shfl_xor(o.y, m);
    float2 n;
    n.x = car * o.x - cai * o.y + cbr * px - cbi * py;
    n.y = car * o.y + cai * o.x + cbr * py + cbi * px;
    sL[k][tid] = n;
  });
}

// ---------- Rot on wave bit (runtime tid-bit index jt in [6,9)) ----------
__device__ __forceinline__ void rot_wave(SARGS, const float* __restrict__ u, const int jt) {
  const int tm = 1 << jt;
  const int pt = tid ^ tm;
  const int bit = (tid >> jt) & 1;
  const float car = bit ? u[6] : u[0], cai = bit ? u[7] : u[1];
  const float cbr = bit ? u[4] : u[2], cbi = bit ? u[5] : u[3];
  static_for<NREG / 4>([&](auto cc) {
    constexpr int c4 = cc.value * 4;
    stg[0][tid] = make_float4(sr[c4 + 0], si[c4 + 0], sr[c4 + 1], si[c4 + 1]);
    stg[1][tid] = make_float4(sr[c4 + 2], si[c4 + 2], sr[c4 + 3], si[c4 + 3]);
    __syncthreads();
    const float4 p0 = stg[0][pt];
    const float4 p1 = stg[1][pt];
    __syncthreads();
    const float prs[4] = {p0.x, p0.z, p1.x, p1.z};
    const float pis[4] = {p0.y, p0.w, p1.y, p1.w};
    static_for<4>([&](auto tc) {
      constexpr int t = tc.value;
      const float orr = sr[c4 + t], oii = si[c4 + t];
      sr[c4 + t] = car * orr - cai * oii + cbr * prs[t] - cbi * pis[t];
      si[c4 + t] = car * oii + cai * orr + cbr * pis[t] + cbi * prs[t];
    });
  });
  static_for<NLDS / 8>([&](auto cc) {
    constexpr int c8 = cc.value * 8;
    float2 nv[8];
    static_for<8>([&](auto jc) {
      constexpr int k = c8 + jc.value;
      const float2 o = sL[k][tid];
      const float2 p = sL[k][pt];
      float2 n;
      n.x = car * o.x - cai * o.y + cbr * p.x - cbi * p.y;
      n.y = car * o.y + cai * o.x + cbr * p.y + cbi * p.x;
      nv[jc.value] = n;
    });
    __syncthreads();
    static_for<8>([&](auto jc) { sL[c8 + jc.value][tid] = nv[jc.value]; });
    __syncthreads();
  });
}

// ---------- CNOT, local-bit target TJ (templated), runtime control cj ----------
template <int TJ>
__device__ __forceinline__ void cnot_local_t(SARGS, const int cj) {
  const int tb7 = tid << 7;
  static_for<64>([&](auto hc) {
    constexpr int h = hc.value;
    constexpr int i0 = ins0<TJ>(h);
    constexpr int i1 = i0 | (1 << TJ);
    const int take = ((i0 | tb7) >> cj) & 1;  // cj != TJ, so same for i0/i1
    const float2 a = ldS<i0>(SPASS);
    const float2 b = ldS<i1>(SPASS);
    const float2 n0 = take ? b : a;
    const float2 n1 = take ? a : b;
    stS<i0>(SPASS, n0);
    stS<i1>(SPASS, n1);
  });
}

// ---------- CNOT, lane-bit target (runtime jm in [0,6)), runtime control ----------
__device__ __forceinline__ void cnot_lane_t(SARGS, const int cj, const int jm) {
  const int m = 1 << jm;
  const int tb7 = tid << 7;
  static_for<NREG>([&](auto ic) {
    constexpr int i = ic.value;
    const int take = ((i | tb7) >> cj) & 1;
    const float pr = __shfl_xor(sr[i], m);
    const float pi = __shfl_xor(si[i], m);
    sr[i] = take ? pr : sr[i];
    si[i] = take ? pi : si[i];
  });
  static_for<NLDS>([&](auto kc) {
    constexpr int k = kc.value;
    const int take = (((NREG + k) | tb7) >> cj) & 1;
    const float2 o = sL[k][tid];
    const float px = __shfl_xor(o.x, m);
    const float py = __shfl_xor(o.y, m);
    float2 n;
    n.x = take ? px : o.x;
    n.y = take ? py : o.y;
    sL[k][tid] = n;
  });
}

// ---------- CNOT, wave-bit target (runtime jt in [6,9)), runtime control ----------
__device__ __forceinline__ void cnot_wave_t(SARGS, const int cj, const int jt) {
  const int tm = 1 << jt;
  const int pt = tid ^ tm;
  const int tb7 = tid << 7;
  static_for<NREG / 4>([&](auto cc) {
    constexpr int c4 = cc.value * 4;
    stg[0][tid] = make_float4(sr[c4 + 0], si[c4 + 0], sr[c4 + 1], si[c4 + 1]);
    stg[1][tid] = make_float4(sr[c4 + 2], si[c4 + 2], sr[c4 + 3], si[c4 + 3]);
    __syncthreads();
    const float4 p0 = stg[0][pt];
    const float4 p1 = stg[1][pt];
    __syncthreads();
    const float prs[4] = {p0.x, p0.z, p1.x, p1.z};
    const float pis[4] = {p0.y, p0.w, p1.y, p1.w};
    static_for<4>([&](auto tc) {
      constexpr int t = tc.value;
      constexpr int a = c4 + t;
      const int take = ((a | tb7) >> cj) & 1;
      sr[a] = take ? prs[t] : sr[a];
      si[a] = take ? pis[t] : si[a];
    });
  });
  static_for<NLDS / 8>([&](auto cc) {
    constexpr int c8 = cc.value * 8;
    float2 nv[8];
    static_for<8>([&](auto jc) {
      constexpr int k = c8 + jc.value;
      const int take = (((NREG + k) | tb7) >> cj) & 1;
      const float2 o = sL[k][tid];
      const float2 p = sL[k][pt];
      float2 n;
      n.x = take ? p.x : o.x;
      n.y = take ? p.y : o.y;
      nv[jc.value] = n;
    });
    __syncthreads();
    static_for<8>([&](auto jc) { sL[c8 + jc.value][tid] = nv[jc.value]; });
    __syncthreads();
  });
}

// Precompute ALL Rot matrices (layers 0..5, batch-shared) into workspace.
__global__ void qsim_prep(const float* __restrict__ w, float* __restrict__ gm) {
  const int i = threadIdx.x;
  if (i < 96) {
    const float phi = w[i * 3 + 0];
    const float th  = w[i * 3 + 1];
    const float om  = w[i * 3 + 2];
    float st, ct; sincosf(0.5f * th, &st, &ct);
    float sa, ca; sincosf(0.5f * (phi + om), &sa, &ca);
    float sb, cb; sincosf(0.5f * (phi - om), &sb, &cb);
    float* u = gm + i * 8;
    u[0] =  ct * ca; u[1] = -ct * sa;   // m00
    u[2] = -st * cb; u[3] = -st * sb;   // m01
    u[4] =  st * cb; u[5] = -st * sb;   // m10
    u[6] =  ct * ca; u[7] =  ct * sa;   // m11
  }
}

__global__ void __launch_bounds__(NTH, 2) qsim_main(const float* __restrict__ x,
                                                    const float* __restrict__ gmG,
                                                    float* __restrict__ out) {
  extern __shared__ char smem_raw[];
  float2 (*sL)[NTH]  = reinterpret_cast<float2(*)[NTH]>(smem_raw);
  float4 (*stg)[NTH] = reinterpret_cast<float4(*)[NTH]>(smem_raw + NLDS * NTH * 8);
  float  (*iv)[4]    = reinterpret_cast<float(*)[4]>(smem_raw + NLDS * NTH * 8);   // aliases stg (init only)
  float  (*red)[16]  = reinterpret_cast<float(*)[16]>(smem_raw + NLDS * NTH * 8);  // aliases stg (epilogue only)

  const int tid = threadIdx.x;
  const int b = blockIdx.x;

  // per-qubit init vector: v = RX(x[b][q]) * |0> = [cos(x/2), -i sin(x/2)]
  if (tid < 16) {
    const int q = tid;
    float xs, xc; sincosf(0.5f * x[b * 16 + q], &xs, &xc);
    iv[q][0] = xc;
    iv[q][1] = 0.f;
    iv[q][2] = 0.f;
    iv[q][3] = -xs;
  }
  __syncthreads();

  float sr[NREG], si[NREG];

  // thread-uniform factor over bits 7..15 (qubits 8..0)
  float Fr = 1.f, Fi = 0.f;
  #pragma unroll
  for (int j = 7; j < 16; ++j) {
    const int q = 15 - j;
    const int bt = (tid >> (j - 7)) & 1;
    const float fr = iv[q][2 * bt], fi = iv[q][2 * bt + 1];
    const float nr = Fr * fr - Fi * fi;
    Fi = Fr * fi + Fi * fr;
    Fr = nr;
  }

  // local tensor doubling over bits 0..6 (qubits 15..9)
  stS<0>(SPASS, make_float2(Fr, Fi));
  static_for<7>([&](auto jc) {
    constexpr int j = jc.value;
    constexpr int m = 1 << j;
    constexpr int q = 15 - j;
    const float f0r = iv[q][0], f0i = iv[q][1];
    const float f1r = iv[q][2], f1i = iv[q][3];
    static_for<m>([&](auto kc) {
      constexpr int k = kc.value;
      const float2 a = ldS<k>(SPASS);
      stS<k | m>(SPASS, make_float2(a.x * f1r - a.y * f1i, a.x * f1i + a.y * f1r));
      stS<k>(SPASS, make_float2(a.x * f0r - a.y * f0i, a.x * f0i + a.y * f0r));
    });
  });
  __syncthreads();  // iv dead -> staging region free

  // 6 layers: 16 Rots (commute; applied j=0..15 i.e. qubit 15..0) then
  // CNOT ring control q=g, target (g+r)%16, r=l+1, in reference order.
  #pragma clang loop unroll(disable)
  for (int l = 0; l < 6; ++l) {
    const float* __restrict__ gmL = gmG + l * 128;
    #pragma clang loop unroll(disable)
    for (int j = 0; j < 16; ++j) {
      const float* __restrict__ u = gmL + (15 - j) * 8;
      if (j < 7) {
        switch (j) {
          case 0: rot_local<0>(SPASS, u); break;
          case 1: rot_local<1>(SPASS, u); break;
          case 2: rot_local<2>(SPASS, u); break;
          case 3: rot_local<3>(SPASS, u); break;
          case 4: rot_local<4>(SPASS, u); break;
          case 5: rot_local<5>(SPASS, u); break;
          default: rot_local<6>(SPASS, u); break;
        }
      } else if (j < 13) {
        rot_lane(SPASS, u, j - 7);
      } else {
        rot_wave(SPASS, u, j - 7);
      }
    }
    const int r = l + 1;
    #pragma clang loop unroll(disable)
    for (int g = 0; g < 16; ++g) {
      const int cj = 15 - g;
      const int tj = 15 - ((g + r) & 15);
      if (tj < 7) {
        switch (tj) {
          case 0: cnot_local_t<0>(SPASS, cj); break;
          case 1: cnot_local_t<1>(SPASS, cj); break;
          case 2: cnot_local_t<2>(SPASS, cj); break;
          case 3: cnot_local_t<3>(SPASS, cj); break;
          case 4: cnot_local_t<4>(SPASS, cj); break;
          case 5: cnot_local_t<5>(SPASS, cj); break;
          default: cnot_local_t<6>(SPASS, cj); break;
        }
      } else if (tj < 13) {
        cnot_lane_t(SPASS, cj, tj - 7);
      } else {
        cnot_wave_t(SPASS, cj, tj - 7);
      }
    }
  }

  // ---- measurement: <Z_q> ----
  float tot = 0.f;
  float sl[7] = {0.f, 0.f, 0.f, 0.f, 0.f, 0.f, 0.f};
  static_for<NREG>([&](auto ic) {
    constexpr int i = ic.value;
    const float p = sr[i] * sr[i] + si[i] * si[i];
    tot += p;
    static_for<7>([&](auto jc) {
      constexpr int j = jc.value;
      sl[j] += (((i >> j) & 1) ? -p : p);
    });
  });
  static_for<NLDS>([&](auto kc) {
    constexpr int k = kc.value;
    constexpr int l = NREG + k;
    const float2 o = sL[k][tid];
    const float p = o.x * o.x + o.y * o.y;
    tot += p;
    static_for<7>([&](auto jc) {
      constexpr int j = jc.value;
      sl[j] += (((l >> j) & 1) ? -p : p);
    });
  });
  __syncthreads();

  static_for<16>([&](auto qc) {
    constexpr int q = qc.value;
    constexpr int j = 15 - q;
    float v;
    if constexpr (j < 7) v = sl[j];
    else v = ((tid >> (j - 7)) & 1) ? -tot : tot;
    v += __shfl_xor(v, 1);
    v += __shfl_xor(v, 2);
    v += __shfl_xor(v, 4);
    v += __shfl_xor(v, 8);
    v += __shfl_xor(v, 16);
    v += __shfl_xor(v, 32);
    if ((tid & 63) == 0) red[tid >> 6][q] = v;
  });
  __syncthreads();
  if (tid < 16) {
    float a = 0.f;
    #pragma unroll
    for (int wv = 0; wv < 8; ++wv) a += red[wv][tid];
    out[b * 16 + tid] = a;
  }
}

extern "C" void kernel_launch(void* const* d_in, const int* in_sizes, int n_in,
                              void* d_out, int out_size, void* d_ws, size_t ws_size,
                              hipStream_t stream) {
  (void)in_sizes; (void)n_in; (void)out_size; (void)ws_size;
  const float* x = (const float*)d_in[0];
  const float* w = (const float*)d_in[1];
  float* out = (float*)d_out;
  float* gm = (float*)d_ws;  // 96*8 floats = 3072 B
  hipFuncSetAttribute(reinterpret_cast<const void*>(qsim_main),
                      hipFuncAttributeMaxDynamicSharedMemorySize, SMEM_BYTES);
  qsim_prep<<<dim3(1), dim3(128), 0, stream>>>(w, gm);
  qsim_main<<<dim3(512), dim3(NTH), SMEM_BYTES, stream>>>(x, gm, out);
}